// Round 10
// baseline (167.763 us; speedup 1.0000x reference)
//
#include <hip/hip_runtime.h>
#include <hip/hip_bf16.h>

#define BN_EPS 1e-5f

typedef __attribute__((ext_vector_type(8))) short bf16x8;
typedef __attribute__((ext_vector_type(4))) float f32x4;

__device__ __forceinline__ unsigned short f2bf(float f) {
    union { float f; unsigned u; } x; x.f = f;
    unsigned u = x.u;
    unsigned r = (u + 0x7fffu + ((u >> 16) & 1u)) >> 16;  // RTNE
    return (unsigned short)r;
}

// ---------------- f32 -> bf16 pre-conversion for x and W in one launch ----------------
__global__ __launch_bounds__(256) void cvt_bf16_kernel(
    const float* __restrict__ x, unsigned short* __restrict__ xb, int nx8,
    const float* __restrict__ W, unsigned short* __restrict__ Wb, int nw8)
{
    int i = blockIdx.x * 256 + threadIdx.x;
    const float* in; unsigned short* out; int idx;
    if (i < nx8) { in = x; out = xb; idx = i; }
    else if (i < nx8 + nw8) { in = W; out = Wb; idx = i - nx8; }
    else return;
    const float4* p = reinterpret_cast<const float4*>(in) + (size_t)idx * 2;
    float4 lo = p[0], hi = p[1];
    union { unsigned short us[8]; uint4 v; } pk;
    pk.us[0] = f2bf(lo.x); pk.us[1] = f2bf(lo.y); pk.us[2] = f2bf(lo.z); pk.us[3] = f2bf(lo.w);
    pk.us[4] = f2bf(hi.x); pk.us[5] = f2bf(hi.y); pk.us[6] = f2bf(hi.z); pk.us[7] = f2bf(hi.w);
    reinterpret_cast<uint4*>(out)[idx] = pk.v;
}

// ---------------- x-resident GEMM + ghostBN + prior-scale ----------------
// Block = 128 rows x 1024 cols, 8 waves (2 row-halves x 4 col-quarters), grid = 256.
// x panel (128x512 bf16 = 128 KB) staged into LDS ONCE (prologue) and reused across
// all 8 col-tiles -> x cache traffic 16x lower than the col-tiled design, and the
// per-K-step stage is only a 16 KB W-tile (2 gload_lds/wave from the L2-hot W half).
// Loop shape per K-step mirrors the r2-proven straight-line STAGE->bar->compute->bar.
// GhostBN per col-tile via the r2-proven red[] exchange (vbatch = block's 128 rows).
__global__ __launch_bounds__(512, 1) void gemm_xres_kernel(
    const unsigned short* __restrict__ xb,  // [B, 512] bf16
    const unsigned short* __restrict__ Wb,  // [2048, 512] bf16
    const float* __restrict__ gamma,
    const float* __restrict__ beta,
    const float* __restrict__ prior,
    float* __restrict__ z,
    int B, int F, int K)
{
    const int tid  = threadIdx.x;
    const int lane = tid & 63;
    const int wid  = tid >> 6;   // 0..7
    const int wr   = wid >> 2;   // 0..1  row half (64 rows)
    const int wn   = wid & 3;    // 0..3  col quarter (32 cols of the 128-col tile)
    const int l15  = lane & 15;
    const int lq   = lane >> 4;

    // XCD swizzle: grid=256, 32 blocks/XCD; XCDs 0-3 -> col-half 0, 4-7 -> col-half 1,
    // so each XCD's W working set is one 1 MB half (L2-resident).
    const int id  = blockIdx.x;
    const int sw  = (id & 7) * 32 + (id >> 3);
    const int rp  = sw & 127;           // row panel 0..127
    const int ch  = sw >> 7;            // col half 0..1
    const int row0 = rp * 128;
    const int colh = ch * 1024;

    __shared__ __align__(16) unsigned short Xs[128 * 512];  // 128 KB, x panel (full K)
    __shared__ __align__(16) unsigned short Ws[128 * 64];   // 16 KB, W tile
    __shared__ float red[2][128][2];                        // 2 KB

    // ---- prologue: stage the x panel once (8192 16B chunks, 16 per thread) ----
    // chunk c -> row = c>>6, slot s = c&63 (16B units); source slot pre-swizzled
    // (s ^ (row&7), low-3-bit XOR) so linear LDS holds the swizzled layout (rule #21).
#pragma unroll
    for (int j = 0; j < 16; ++j) {
        int c = wid * 1024 + j * 64 + lane;
        int row = c >> 6;
        int s   = c & 63;
        int ssrc = s ^ (row & 7);
        unsigned ldsoff = (unsigned)(wid * 1024 + j * 64) * 16;  // wave-uniform bytes
        const unsigned short* g = xb + (size_t)(row0 + row) * K + ssrc * 8;
        __builtin_amdgcn_global_load_lds(
            (const __attribute__((address_space(1))) void*)g,
            (__attribute__((address_space(3))) void*)((char*)Xs + ldsoff), 16, 0, 0);
    }

    for (int ct = 0; ct < 8; ++ct) {
        const int col0 = colh + ct * 128;

        f32x4 acc[4][2];
        const f32x4 zero = {0.f, 0.f, 0.f, 0.f};
#pragma unroll
        for (int m = 0; m < 4; ++m) { acc[m][0] = zero; acc[m][1] = zero; }

        for (int t = 0; t < 8; ++t) {
            // ---- stage W tile (128 cols x 64 K = 16 KB), straight-line ----
#pragma unroll
            for (int j = 0; j < 2; ++j) {
                int c = wid * 128 + j * 64 + lane;
                int row = c >> 3;
                int s   = c & 7;
                int ssrc = s ^ (row & 7);
                unsigned ldsoff = (unsigned)(wid * 128 + j * 64) * 16;  // wave-uniform
                const unsigned short* g = Wb + (size_t)(col0 + row) * K + t * 64 + ssrc * 8;
                __builtin_amdgcn_global_load_lds(
                    (const __attribute__((address_space(1))) void*)g,
                    (__attribute__((address_space(3))) void*)((char*)Ws + ldsoff), 16, 0, 0);
            }
            __syncthreads();   // drains W stage (and prologue x stage on first pass)

#pragma unroll
            for (int ks = 0; ks < 2; ++ks) {
                bf16x8 af[4], bf[2];
#pragma unroll
                for (int m = 0; m < 4; ++m) {
                    int r = wr * 64 + m * 16 + l15;
                    int s = t * 8 + ks * 4 + lq;
                    af[m] = *reinterpret_cast<const bf16x8*>(&Xs[r * 512 + ((s ^ (r & 7)) * 8)]);
                }
#pragma unroll
                for (int n = 0; n < 2; ++n) {
                    int r = wn * 32 + n * 16 + l15;
                    int s = ks * 4 + lq;
                    bf[n] = *reinterpret_cast<const bf16x8*>(&Ws[r * 64 + ((s ^ (r & 7)) * 8)]);
                }
#pragma unroll
                for (int m = 0; m < 4; ++m)
#pragma unroll
                    for (int n = 0; n < 2; ++n)
                        acc[m][n] = __builtin_amdgcn_mfma_f32_16x16x32_bf16(af[m], bf[n], acc[m][n], 0, 0, 0);
            }
            __syncthreads();   // all waves done reading Ws; safe to overwrite next t
        }

        // ---- GhostBN stats for this col-tile (128 rows = the block's vbatch) ----
        float psum[2], psq[2];
#pragma unroll
        for (int n = 0; n < 2; ++n) {
            float s = 0.f, q = 0.f;
#pragma unroll
            for (int m = 0; m < 4; ++m)
#pragma unroll
                for (int r = 0; r < 4; ++r) { float v = acc[m][n][r]; s += v; q += v * v; }
            s += __shfl_xor(s, 16); q += __shfl_xor(q, 16);
            s += __shfl_xor(s, 32); q += __shfl_xor(q, 32);
            psum[n] = s; psq[n] = q;
        }
        if (lane < 16) {
#pragma unroll
            for (int n = 0; n < 2; ++n) {
                red[wr][wn * 32 + n * 16 + lane][0] = psum[n];
                red[wr][wn * 32 + n * 16 + lane][1] = psq[n];
            }
        }
        __syncthreads();

        // ---- epilogue: BN + prior scale, store z for this col-tile ----
#pragma unroll
        for (int n = 0; n < 2; ++n) {
            int cl = wn * 32 + n * 16 + l15;
            int cg = col0 + cl;
            float tot = red[0][cl][0] + red[1][cl][0];
            float tsq = red[0][cl][1] + red[1][cl][1];
            float mu  = tot * (1.f / 128.f);
            float var = tsq * (1.f / 128.f) - mu * mu;
            float rv  = rsqrtf(var + BN_EPS);
            float g   = gamma[cg] * rv;
            float bt  = beta[cg] - mu * g;
#pragma unroll
            for (int m = 0; m < 4; ++m) {
#pragma unroll
                for (int r = 0; r < 4; ++r) {
                    int rg = row0 + wr * 64 + m * 16 + lq * 4 + r;
                    size_t idx = (size_t)rg * F + cg;
                    z[idx] = (acc[m][n][r] * g + bt) * prior[idx];
                }
            }
        }
        // next ct's W stage only writes Ws (not read by the epilogue); its trailing
        // barrier syncs everyone before Ws is consumed, and red[] is re-written only
        // after 8 more barrier pairs -> no race.
    }
}

// ---------------- r9 kernel (proven): 128x128 col-tiled, kept as fallback ----------------
__global__ __launch_bounds__(256, 4) void gemm_bn_lds_kernel(
    const unsigned short* __restrict__ xb, const unsigned short* __restrict__ Wb,
    const float* __restrict__ gamma, const float* __restrict__ beta,
    const float* __restrict__ prior, float* __restrict__ z,
    int B, int F, int K)
{
    const int tid  = threadIdx.x;
    const int lane = tid & 63;
    const int wid  = tid >> 6;
    const int wr   = wid >> 1;
    const int wc   = wid & 1;
    const int l15  = lane & 15;
    const int lq   = lane >> 4;

    const int nwg = gridDim.x;
    const int cpx = nwg >> 3;
    const int id  = blockIdx.x;
    const int sw  = (id & 7) * cpx + (id >> 3);
    const int nbx = F >> 7;
    const int bx  = sw & (nbx - 1);
    const int by  = sw / nbx;
    const int row0 = by * 128;
    const int col0 = bx * 128;

    __shared__ __align__(16) unsigned short As[128 * 64];
    __shared__ __align__(16) unsigned short Bs[128 * 64];
    __shared__ float red[2][128][2];

    f32x4 acc[4][4];
    const f32x4 zero = {0.f, 0.f, 0.f, 0.f};
#pragma unroll
    for (int m = 0; m < 4; ++m)
#pragma unroll
        for (int n = 0; n < 4; ++n) acc[m][n] = zero;

    const int cbase = wid * 256 + lane;

    for (int k0 = 0; k0 < K; k0 += 64) {
#pragma unroll
        for (int j = 0; j < 4; ++j) {
            int c = cbase + j * 64;
            int row = c >> 3;
            int s_src = (c & 7) ^ (row & 7);
            unsigned ldsoff = (unsigned)(wid * 4 + j) * 1024;
            {
                const unsigned short* g = xb + (size_t)(row0 + row) * K + k0 + s_src * 8;
                __builtin_amdgcn_global_load_lds(
                    (const __attribute__((address_space(1))) void*)g,
                    (__attribute__((address_space(3))) void*)((char*)As + ldsoff), 16, 0, 0);
            }
            {
                const unsigned short* g = Wb + (size_t)(col0 + row) * K + k0 + s_src * 8;
                __builtin_amdgcn_global_load_lds(
                    (const __attribute__((address_space(1))) void*)g,
                    (__attribute__((address_space(3))) void*)((char*)Bs + ldsoff), 16, 0, 0);
            }
        }
        __syncthreads();

#pragma unroll
        for (int ks = 0; ks < 2; ++ks) {
            bf16x8 af[4], bfr[4];
#pragma unroll
            for (int m = 0; m < 4; ++m) {
                int r = wr * 64 + m * 16 + l15;
                int s = ks * 4 + lq;
                af[m] = *reinterpret_cast<const bf16x8*>(&As[r * 64 + ((s ^ (r & 7)) * 8)]);
            }
#pragma unroll
            for (int n = 0; n < 4; ++n) {
                int r = wc * 64 + n * 16 + l15;
                int s = ks * 4 + lq;
                bfr[n] = *reinterpret_cast<const bf16x8*>(&Bs[r * 64 + ((s ^ (r & 7)) * 8)]);
            }
#pragma unroll
            for (int m = 0; m < 4; ++m)
#pragma unroll
                for (int n = 0; n < 4; ++n)
                    acc[m][n] = __builtin_amdgcn_mfma_f32_16x16x32_bf16(af[m], bfr[n], acc[m][n], 0, 0, 0);
        }
        __syncthreads();
    }

    float psum[4], psq[4];
#pragma unroll
    for (int n = 0; n < 4; ++n) {
        float s = 0.f, q = 0.f;
#pragma unroll
        for (int m = 0; m < 4; ++m)
#pragma unroll
            for (int r = 0; r < 4; ++r) { float v = acc[m][n][r]; s += v; q += v * v; }
        s += __shfl_xor(s, 16); q += __shfl_xor(q, 16);
        s += __shfl_xor(s, 32); q += __shfl_xor(q, 32);
        psum[n] = s; psq[n] = q;
    }
    if (lane < 16) {
#pragma unroll
        for (int n = 0; n < 4; ++n) {
            red[wr][wc * 64 + n * 16 + lane][0] = psum[n];
            red[wr][wc * 64 + n * 16 + lane][1] = psq[n];
        }
    }
    __syncthreads();

#pragma unroll
    for (int n = 0; n < 4; ++n) {
        int cl = wc * 64 + n * 16 + l15;
        int cg = col0 + cl;
        float tot = red[0][cl][0] + red[1][cl][0];
        float tsq = red[0][cl][1] + red[1][cl][1];
        float mu  = tot * (1.f / 128.f);
        float var = tsq * (1.f / 128.f) - mu * mu;
        float rv  = rsqrtf(var + BN_EPS);
        float g   = gamma[cg] * rv;
        float bt  = beta[cg] - mu * g;
#pragma unroll
        for (int m = 0; m < 4; ++m) {
#pragma unroll
            for (int r = 0; r < 4; ++r) {
                int rg = row0 + wr * 64 + m * 16 + lq * 4 + r;
                size_t idx = (size_t)rg * F + cg;
                z[idx] = (acc[m][n][r] * g + bt) * prior[idx];
            }
        }
    }
}

// ---------------- fallback (f32 inputs, in-loop convert) ----------------
__global__ __launch_bounds__(256, 2) void gemm_bn_kernel(
    const float* __restrict__ x, const float* __restrict__ W,
    const float* __restrict__ gamma, const float* __restrict__ beta,
    const float* __restrict__ prior, float* __restrict__ z,
    int B, int F, int K)
{
    const int tid  = threadIdx.x;
    const int lane = tid & 63;
    const int wid  = tid >> 6;
    const int wr   = wid >> 1;
    const int wc   = wid & 1;
    const int row0 = blockIdx.y * 128;
    const int col0 = blockIdx.x * 128;
    const int l15  = lane & 15;
    const int lq   = lane >> 4;

    __shared__ __align__(16) unsigned short As[128 * 64];
    __shared__ __align__(16) unsigned short Bs[128 * 64];
    __shared__ float red[2][128][2];

    f32x4 acc[4][4];
    const f32x4 zero = {0.f, 0.f, 0.f, 0.f};
#pragma unroll
    for (int m = 0; m < 4; ++m)
#pragma unroll
        for (int n = 0; n < 4; ++n) acc[m][n] = zero;

    for (int k0 = 0; k0 < K; k0 += 64) {
#pragma unroll
        for (int i = 0; i < 4; ++i) {
            int c = tid + i * 256;
            int r = c >> 3;
            int s = c & 7;
            {
                const float4* pa = reinterpret_cast<const float4*>(x + (size_t)(row0 + r) * K + k0 + s * 8);
                float4 lo = pa[0], hi = pa[1];
                union { unsigned short us[8]; uint4 v; } pk;
                pk.us[0] = f2bf(lo.x); pk.us[1] = f2bf(lo.y); pk.us[2] = f2bf(lo.z); pk.us[3] = f2bf(lo.w);
                pk.us[4] = f2bf(hi.x); pk.us[5] = f2bf(hi.y); pk.us[6] = f2bf(hi.z); pk.us[7] = f2bf(hi.w);
                *reinterpret_cast<uint4*>(&As[r * 64 + ((s ^ (r & 7)) * 8)]) = pk.v;
            }
            {
                const float4* pb = reinterpret_cast<const float4*>(W + (size_t)(col0 + r) * K + k0 + s * 8);
                float4 lo = pb[0], hi = pb[1];
                union { unsigned short us[8]; uint4 v; } pk;
                pk.us[0] = f2bf(lo.x); pk.us[1] = f2bf(lo.y); pk.us[2] = f2bf(lo.z); pk.us[3] = f2bf(lo.w);
                pk.us[4] = f2bf(hi.x); pk.us[5] = f2bf(hi.y); pk.us[6] = f2bf(hi.z); pk.us[7] = f2bf(hi.w);
                *reinterpret_cast<uint4*>(&Bs[r * 64 + ((s ^ (r & 7)) * 8)]) = pk.v;
            }
        }
        __syncthreads();
#pragma unroll
        for (int ks = 0; ks < 2; ++ks) {
            bf16x8 af[4], bfr[4];
#pragma unroll
            for (int m = 0; m < 4; ++m) {
                int r = wr * 64 + m * 16 + l15;
                int s = ks * 4 + lq;
                af[m] = *reinterpret_cast<const bf16x8*>(&As[r * 64 + ((s ^ (r & 7)) * 8)]);
            }
#pragma unroll
            for (int n = 0; n < 4; ++n) {
                int r = wc * 64 + n * 16 + l15;
                int s = ks * 4 + lq;
                bfr[n] = *reinterpret_cast<const bf16x8*>(&Bs[r * 64 + ((s ^ (r & 7)) * 8)]);
            }
#pragma unroll
            for (int m = 0; m < 4; ++m)
#pragma unroll
                for (int n = 0; n < 4; ++n)
                    acc[m][n] = __builtin_amdgcn_mfma_f32_16x16x32_bf16(af[m], bfr[n], acc[m][n], 0, 0, 0);
        }
        __syncthreads();
    }

    float psum[4], psq[4];
#pragma unroll
    for (int n = 0; n < 4; ++n) {
        float s = 0.f, q = 0.f;
#pragma unroll
        for (int m = 0; m < 4; ++m)
#pragma unroll
            for (int r = 0; r < 4; ++r) { float v = acc[m][n][r]; s += v; q += v * v; }
        s += __shfl_xor(s, 16); q += __shfl_xor(q, 16);
        s += __shfl_xor(s, 32); q += __shfl_xor(q, 32);
        psum[n] = s; psq[n] = q;
    }
    if (lane < 16) {
#pragma unroll
        for (int n = 0; n < 4; ++n) {
            red[wr][wc * 64 + n * 16 + lane][0] = psum[n];
            red[wr][wc * 64 + n * 16 + lane][1] = psq[n];
        }
    }
    __syncthreads();

#pragma unroll
    for (int n = 0; n < 4; ++n) {
        int cl = wc * 64 + n * 16 + l15;
        int cg = col0 + cl;
        float tot = red[0][cl][0] + red[1][cl][0];
        float tsq = red[0][cl][1] + red[1][cl][1];
        float mu  = tot * (1.f / 128.f);
        float var = tsq * (1.f / 128.f) - mu * mu;
        float rv  = rsqrtf(var + BN_EPS);
        float g   = gamma[cg] * rv;
        float bt  = beta[cg] - mu * g;
#pragma unroll
        for (int m = 0; m < 4; ++m) {
#pragma unroll
            for (int r = 0; r < 4; ++r) {
                int rg = row0 + wr * 64 + m * 16 + lq * 4 + r;
                size_t idx = (size_t)rg * F + cg;
                z[idx] = (acc[m][n][r] * g + bt) * prior[idx];
            }
        }
    }
}

// ---------------- sparsemax (Michelot fixed-point), one wave per row ----------------
__global__ __launch_bounds__(256, 4) void sparsemax_kernel(float* __restrict__ z, int B, int F)
{
    const int lane = threadIdx.x & 63;
    const int wid  = threadIdx.x >> 6;
    const int row  = blockIdx.x * 4 + wid;
    if (row >= B) return;
    float* rp = z + (size_t)row * F;

    float4 v[8];
    float s = 0.f;
#pragma unroll
    for (int j = 0; j < 8; ++j) {
        v[j] = reinterpret_cast<const float4*>(rp)[j * 64 + lane];
        s += v[j].x + v[j].y + v[j].z + v[j].w;
    }
#pragma unroll
    for (int o = 32; o; o >>= 1) s += __shfl_xor(s, o);

    float tau = (s - 1.f) / (float)F;
    int cprev = F;
    for (int it = 0; it < 64; ++it) {
        float s2 = 0.f; int c2 = 0;
#pragma unroll
        for (int j = 0; j < 8; ++j) {
            if (v[j].x > tau) { s2 += v[j].x; ++c2; }
            if (v[j].y > tau) { s2 += v[j].y; ++c2; }
            if (v[j].z > tau) { s2 += v[j].z; ++c2; }
            if (v[j].w > tau) { s2 += v[j].w; ++c2; }
        }
#pragma unroll
        for (int o = 32; o; o >>= 1) { s2 += __shfl_xor(s2, o); c2 += __shfl_xor(c2, o); }
        if (c2 == cprev) break;
        tau = (s2 - 1.f) / (float)c2;
        cprev = c2;
    }

#pragma unroll
    for (int j = 0; j < 8; ++j) {
        float4 o4;
        o4.x = fmaxf(v[j].x - tau, 0.f);
        o4.y = fmaxf(v[j].y - tau, 0.f);
        o4.z = fmaxf(v[j].z - tau, 0.f);
        o4.w = fmaxf(v[j].w - tau, 0.f);
        reinterpret_cast<float4*>(rp)[j * 64 + lane] = o4;
    }
}

extern "C" void kernel_launch(void* const* d_in, const int* in_sizes, int n_in,
                              void* d_out, int out_size, void* d_ws, size_t ws_size,
                              hipStream_t stream) {
    const float* x     = (const float*)d_in[0];
    const float* prior = (const float*)d_in[1];
    const float* W     = (const float*)d_in[2];
    const float* gamma = (const float*)d_in[3];
    const float* beta  = (const float*)d_in[4];
    float* out = (float*)d_out;

    const int F = in_sizes[3];              // 2048
    const int K = in_sizes[2] / F;          // 512
    const int B = in_sizes[0] / K;          // 16384

    const size_t nx = (size_t)B * K;
    const size_t nw = (size_t)F * K;
    const size_t need = (nx + nw) * sizeof(unsigned short);

    if (ws_size >= need) {
        unsigned short* xb = (unsigned short*)d_ws;
        unsigned short* Wb = xb + nx;
        int nx8 = (int)(nx / 8), nw8 = (int)(nw / 8);
        int tot8 = nx8 + nw8;
        cvt_bf16_kernel<<<dim3((tot8 + 255) / 256), dim3(256), 0, stream>>>(x, xb, nx8, W, Wb, nw8);
        if (K == 512 && F == 2048 && (B % 128) == 0 && ((B / 128) * 2) % 8 == 0) {
            int nwg = (B / 128) * 2;        // 256
            gemm_xres_kernel<<<dim3(nwg), dim3(512), 0, stream>>>(xb, Wb, gamma, beta, prior, out, B, F, K);
        } else {
            int nwg = (F / 128) * (B / 128);
            gemm_bn_lds_kernel<<<dim3(nwg), dim3(256), 0, stream>>>(xb, Wb, gamma, beta, prior, out, B, F, K);
        }
    } else {
        dim3 g1(F / 128, B / 128);
        gemm_bn_kernel<<<g1, dim3(256), 0, stream>>>(x, W, gamma, beta, prior, out, B, F, K);
    }
    sparsemax_kernel<<<dim3(B / 4), dim3(256), 0, stream>>>(out, B, F);
}

// Round 11
// 146.353 us; speedup vs baseline: 1.1463x; 1.1463x over previous
//
#include <hip/hip_runtime.h>
#include <hip/hip_bf16.h>

#define BN_EPS 1e-5f

typedef __attribute__((ext_vector_type(8))) short bf16x8;
typedef __attribute__((ext_vector_type(4))) float f32x4;

__device__ __forceinline__ unsigned short f2bf(float f) {
    union { float f; unsigned u; } x; x.f = f;
    unsigned u = x.u;
    unsigned r = (u + 0x7fffu + ((u >> 16) & 1u)) >> 16;  // RTNE
    return (unsigned short)r;
}

// ---------------- f32 -> bf16 pre-conversion for x and W in one launch ----------------
__global__ __launch_bounds__(256) void cvt_bf16_kernel(
    const float* __restrict__ x, unsigned short* __restrict__ xb, int nx8,
    const float* __restrict__ W, unsigned short* __restrict__ Wb, int nw8)
{
    int i = blockIdx.x * 256 + threadIdx.x;
    const float* in; unsigned short* out; int idx;
    if (i < nx8) { in = x; out = xb; idx = i; }
    else if (i < nx8 + nw8) { in = W; out = Wb; idx = i - nx8; }
    else return;
    const float4* p = reinterpret_cast<const float4*>(in) + (size_t)idx * 2;
    float4 lo = p[0], hi = p[1];
    union { unsigned short us[8]; uint4 v; } pk;
    pk.us[0] = f2bf(lo.x); pk.us[1] = f2bf(lo.y); pk.us[2] = f2bf(lo.z); pk.us[3] = f2bf(lo.w);
    pk.us[4] = f2bf(hi.x); pk.us[5] = f2bf(hi.y); pk.us[6] = f2bf(hi.z); pk.us[7] = f2bf(hi.w);
    reinterpret_cast<uint4*>(out)[idx] = pk.v;
}

// ---------------- 128x256-tile GEMM + ghostBN + prior-scale ----------------
// r9's proven structure (single-buffer LDS, straight-line STAGE->bar->compute->bar,
// global_load_lds w=16, src-side XOR swizzle at 64-elem row stride — the geometry
// measured 0-conflict) with BN=256: halves block count -> halves stage-drains/CU and
// halves x's L2 re-read traffic. 8 waves (2 row-halves x 4 col-quarters), 512 thr.
// LDS = 16 (As) + 32 (Bs) + 4 (red) = 52 KB -> 3 blocks/CU LDS-wise; VGPR <= ~128.
__global__ __launch_bounds__(512, 2) void gemm_bn_256n_kernel(
    const unsigned short* __restrict__ xb,  // [B, K] bf16
    const unsigned short* __restrict__ Wb,  // [F, K] bf16
    const float* __restrict__ gamma,
    const float* __restrict__ beta,
    const float* __restrict__ prior,
    float* __restrict__ z,
    int B, int F, int K)
{
    const int tid  = threadIdx.x;
    const int lane = tid & 63;
    const int wid  = tid >> 6;   // 0..7
    const int wr   = wid >> 2;   // 0..1  row half (64 rows)
    const int wn   = wid & 3;    // 0..3  col quarter (64 cols)
    const int l15  = lane & 15;
    const int lq   = lane >> 4;

    // XCD-chunked bijective swizzle (nwg = 1024, divisible by 8), bx-inner.
    const int nwg = gridDim.x;
    const int cpx = nwg >> 3;
    const int id  = blockIdx.x;
    const int sw  = (id & 7) * cpx + (id >> 3);
    const int nbx = F >> 8;                 // 8 col-blocks
    const int bx  = sw & (nbx - 1);
    const int by  = sw / nbx;
    const int row0 = by * 128;
    const int col0 = bx * 256;

    __shared__ __align__(16) unsigned short As[128 * 64];  // 16 KB
    __shared__ __align__(16) unsigned short Bs[256 * 64];  // 32 KB
    __shared__ float red[2][256][2];                       // 4 KB

    f32x4 acc[4][4];
    const f32x4 zero = {0.f, 0.f, 0.f, 0.f};
#pragma unroll
    for (int m = 0; m < 4; ++m)
#pragma unroll
        for (int n = 0; n < 4; ++n) acc[m][n] = zero;

    for (int k0 = 0; k0 < K; k0 += 64) {
        // ---- STAGE A (128x64, 1024 chunks) + B (256x64, 2048 chunks), straight-line ----
#pragma unroll
        for (int j = 0; j < 2; ++j) {
            int c = wid * 128 + j * 64 + lane;
            int row = c >> 3;
            int s_src = (c & 7) ^ (row & 7);
            unsigned ldsoff = (unsigned)(wid * 128 + j * 64) * 16;  // wave-uniform bytes
            const unsigned short* g = xb + (size_t)(row0 + row) * K + k0 + s_src * 8;
            __builtin_amdgcn_global_load_lds(
                (const __attribute__((address_space(1))) void*)g,
                (__attribute__((address_space(3))) void*)((char*)As + ldsoff), 16, 0, 0);
        }
#pragma unroll
        for (int j = 0; j < 4; ++j) {
            int c = wid * 256 + j * 64 + lane;
            int row = c >> 3;
            int s_src = (c & 7) ^ (row & 7);
            unsigned ldsoff = (unsigned)(wid * 256 + j * 64) * 16;  // wave-uniform bytes
            const unsigned short* g = Wb + (size_t)(col0 + row) * K + k0 + s_src * 8;
            __builtin_amdgcn_global_load_lds(
                (const __attribute__((address_space(1))) void*)g,
                (__attribute__((address_space(3))) void*)((char*)Bs + ldsoff), 16, 0, 0);
        }
        __syncthreads();

#pragma unroll
        for (int ks = 0; ks < 2; ++ks) {
            bf16x8 af[4], bfr[4];
#pragma unroll
            for (int m = 0; m < 4; ++m) {
                int r = wr * 64 + m * 16 + l15;
                int s = ks * 4 + lq;
                af[m] = *reinterpret_cast<const bf16x8*>(&As[r * 64 + ((s ^ (r & 7)) * 8)]);
            }
#pragma unroll
            for (int n = 0; n < 4; ++n) {
                int r = wn * 64 + n * 16 + l15;
                int s = ks * 4 + lq;
                bfr[n] = *reinterpret_cast<const bf16x8*>(&Bs[r * 64 + ((s ^ (r & 7)) * 8)]);
            }
#pragma unroll
            for (int m = 0; m < 4; ++m)
#pragma unroll
                for (int n = 0; n < 4; ++n)
                    acc[m][n] = __builtin_amdgcn_mfma_f32_16x16x32_bf16(af[m], bfr[n], acc[m][n], 0, 0, 0);
        }
        __syncthreads();
    }

    // ---- GhostBN stats: per-column sum/sumsq over the block's 128 rows ----
    float psum[4], psq[4];
#pragma unroll
    for (int n = 0; n < 4; ++n) {
        float s = 0.f, q = 0.f;
#pragma unroll
        for (int m = 0; m < 4; ++m)
#pragma unroll
            for (int r = 0; r < 4; ++r) { float v = acc[m][n][r]; s += v; q += v * v; }
        s += __shfl_xor(s, 16); q += __shfl_xor(q, 16);
        s += __shfl_xor(s, 32); q += __shfl_xor(q, 32);
        psum[n] = s; psq[n] = q;
    }
    if (lane < 16) {
#pragma unroll
        for (int n = 0; n < 4; ++n) {
            red[wr][wn * 64 + n * 16 + lane][0] = psum[n];
            red[wr][wn * 64 + n * 16 + lane][1] = psq[n];
        }
    }
    __syncthreads();

    // ---- epilogue: BN + prior scale, read prior at store site ----
#pragma unroll
    for (int n = 0; n < 4; ++n) {
        int cl = wn * 64 + n * 16 + l15;
        int cg = col0 + cl;
        float tot = red[0][cl][0] + red[1][cl][0];
        float tsq = red[0][cl][1] + red[1][cl][1];
        float mu  = tot * (1.f / 128.f);
        float var = tsq * (1.f / 128.f) - mu * mu;
        float rv  = rsqrtf(var + BN_EPS);
        float g   = gamma[cg] * rv;
        float bt  = beta[cg] - mu * g;
#pragma unroll
        for (int m = 0; m < 4; ++m) {
#pragma unroll
            for (int r = 0; r < 4; ++r) {
                int rg = row0 + wr * 64 + m * 16 + lq * 4 + r;
                size_t idx = (size_t)rg * F + cg;
                z[idx] = (acc[m][n][r] * g + bt) * prior[idx];
            }
        }
    }
}

// ---------------- fallback (f32 inputs, in-loop convert) ----------------
__global__ __launch_bounds__(256, 2) void gemm_bn_kernel(
    const float* __restrict__ x, const float* __restrict__ W,
    const float* __restrict__ gamma, const float* __restrict__ beta,
    const float* __restrict__ prior, float* __restrict__ z,
    int B, int F, int K)
{
    const int tid  = threadIdx.x;
    const int lane = tid & 63;
    const int wid  = tid >> 6;
    const int wr   = wid >> 1;
    const int wc   = wid & 1;
    const int row0 = blockIdx.y * 128;
    const int col0 = blockIdx.x * 128;
    const int l15  = lane & 15;
    const int lq   = lane >> 4;

    __shared__ __align__(16) unsigned short As[128 * 64];
    __shared__ __align__(16) unsigned short Bs[128 * 64];
    __shared__ float red[2][128][2];

    f32x4 acc[4][4];
    const f32x4 zero = {0.f, 0.f, 0.f, 0.f};
#pragma unroll
    for (int m = 0; m < 4; ++m)
#pragma unroll
        for (int n = 0; n < 4; ++n) acc[m][n] = zero;

    for (int k0 = 0; k0 < K; k0 += 64) {
#pragma unroll
        for (int i = 0; i < 4; ++i) {
            int c = tid + i * 256;
            int r = c >> 3;
            int s = c & 7;
            {
                const float4* pa = reinterpret_cast<const float4*>(x + (size_t)(row0 + r) * K + k0 + s * 8);
                float4 lo = pa[0], hi = pa[1];
                union { unsigned short us[8]; uint4 v; } pk;
                pk.us[0] = f2bf(lo.x); pk.us[1] = f2bf(lo.y); pk.us[2] = f2bf(lo.z); pk.us[3] = f2bf(lo.w);
                pk.us[4] = f2bf(hi.x); pk.us[5] = f2bf(hi.y); pk.us[6] = f2bf(hi.z); pk.us[7] = f2bf(hi.w);
                *reinterpret_cast<uint4*>(&As[r * 64 + ((s ^ (r & 7)) * 8)]) = pk.v;
            }
            {
                const float4* pb = reinterpret_cast<const float4*>(W + (size_t)(col0 + r) * K + k0 + s * 8);
                float4 lo = pb[0], hi = pb[1];
                union { unsigned short us[8]; uint4 v; } pk;
                pk.us[0] = f2bf(lo.x); pk.us[1] = f2bf(lo.y); pk.us[2] = f2bf(lo.z); pk.us[3] = f2bf(lo.w);
                pk.us[4] = f2bf(hi.x); pk.us[5] = f2bf(hi.y); pk.us[6] = f2bf(hi.z); pk.us[7] = f2bf(hi.w);
                *reinterpret_cast<uint4*>(&Bs[r * 64 + ((s ^ (r & 7)) * 8)]) = pk.v;
            }
        }
        __syncthreads();
#pragma unroll
        for (int ks = 0; ks < 2; ++ks) {
            bf16x8 af[4], bfr[4];
#pragma unroll
            for (int m = 0; m < 4; ++m) {
                int r = wr * 64 + m * 16 + l15;
                int s = ks * 4 + lq;
                af[m] = *reinterpret_cast<const bf16x8*>(&As[r * 64 + ((s ^ (r & 7)) * 8)]);
            }
#pragma unroll
            for (int n = 0; n < 4; ++n) {
                int r = wc * 64 + n * 16 + l15;
                int s = ks * 4 + lq;
                bfr[n] = *reinterpret_cast<const bf16x8*>(&Bs[r * 64 + ((s ^ (r & 7)) * 8)]);
            }
#pragma unroll
            for (int m = 0; m < 4; ++m)
#pragma unroll
                for (int n = 0; n < 4; ++n)
                    acc[m][n] = __builtin_amdgcn_mfma_f32_16x16x32_bf16(af[m], bfr[n], acc[m][n], 0, 0, 0);
        }
        __syncthreads();
    }

    float psum[4], psq[4];
#pragma unroll
    for (int n = 0; n < 4; ++n) {
        float s = 0.f, q = 0.f;
#pragma unroll
        for (int m = 0; m < 4; ++m)
#pragma unroll
            for (int r = 0; r < 4; ++r) { float v = acc[m][n][r]; s += v; q += v * v; }
        s += __shfl_xor(s, 16); q += __shfl_xor(q, 16);
        s += __shfl_xor(s, 32); q += __shfl_xor(q, 32);
        psum[n] = s; psq[n] = q;
    }
    if (lane < 16) {
#pragma unroll
        for (int n = 0; n < 4; ++n) {
            red[wr][wc * 64 + n * 16 + lane][0] = psum[n];
            red[wr][wc * 64 + n * 16 + lane][1] = psq[n];
        }
    }
    __syncthreads();

#pragma unroll
    for (int n = 0; n < 4; ++n) {
        int cl = wc * 64 + n * 16 + l15;
        int cg = col0 + cl;
        float tot = red[0][cl][0] + red[1][cl][0];
        float tsq = red[0][cl][1] + red[1][cl][1];
        float mu  = tot * (1.f / 128.f);
        float var = tsq * (1.f / 128.f) - mu * mu;
        float rv  = rsqrtf(var + BN_EPS);
        float g   = gamma[cg] * rv;
        float bt  = beta[cg] - mu * g;
#pragma unroll
        for (int m = 0; m < 4; ++m) {
#pragma unroll
            for (int r = 0; r < 4; ++r) {
                int rg = row0 + wr * 64 + m * 16 + lq * 4 + r;
                size_t idx = (size_t)rg * F + cg;
                z[idx] = (acc[m][n][r] * g + bt) * prior[idx];
            }
        }
    }
}

// ---------------- sparsemax (Michelot fixed-point), one wave per row ----------------
__global__ __launch_bounds__(256, 4) void sparsemax_kernel(float* __restrict__ z, int B, int F)
{
    const int lane = threadIdx.x & 63;
    const int wid  = threadIdx.x >> 6;
    const int row  = blockIdx.x * 4 + wid;
    if (row >= B) return;
    float* rp = z + (size_t)row * F;

    float4 v[8];
    float s = 0.f;
#pragma unroll
    for (int j = 0; j < 8; ++j) {
        v[j] = reinterpret_cast<const float4*>(rp)[j * 64 + lane];
        s += v[j].x + v[j].y + v[j].z + v[j].w;
    }
#pragma unroll
    for (int o = 32; o; o >>= 1) s += __shfl_xor(s, o);

    float tau = (s - 1.f) / (float)F;
    int cprev = F;
    for (int it = 0; it < 64; ++it) {
        float s2 = 0.f; int c2 = 0;
#pragma unroll
        for (int j = 0; j < 8; ++j) {
            if (v[j].x > tau) { s2 += v[j].x; ++c2; }
            if (v[j].y > tau) { s2 += v[j].y; ++c2; }
            if (v[j].z > tau) { s2 += v[j].z; ++c2; }
            if (v[j].w > tau) { s2 += v[j].w; ++c2; }
        }
#pragma unroll
        for (int o = 32; o; o >>= 1) { s2 += __shfl_xor(s2, o); c2 += __shfl_xor(c2, o); }
        if (c2 == cprev) break;
        tau = (s2 - 1.f) / (float)c2;
        cprev = c2;
    }

#pragma unroll
    for (int j = 0; j < 8; ++j) {
        float4 o4;
        o4.x = fmaxf(v[j].x - tau, 0.f);
        o4.y = fmaxf(v[j].y - tau, 0.f);
        o4.z = fmaxf(v[j].z - tau, 0.f);
        o4.w = fmaxf(v[j].w - tau, 0.f);
        reinterpret_cast<float4*>(rp)[j * 64 + lane] = o4;
    }
}

extern "C" void kernel_launch(void* const* d_in, const int* in_sizes, int n_in,
                              void* d_out, int out_size, void* d_ws, size_t ws_size,
                              hipStream_t stream) {
    const float* x     = (const float*)d_in[0];
    const float* prior = (const float*)d_in[1];
    const float* W     = (const float*)d_in[2];
    const float* gamma = (const float*)d_in[3];
    const float* beta  = (const float*)d_in[4];
    float* out = (float*)d_out;

    const int F = in_sizes[3];              // 2048
    const int K = in_sizes[2] / F;          // 512
    const int B = in_sizes[0] / K;          // 16384

    const size_t nx = (size_t)B * K;
    const size_t nw = (size_t)F * K;
    const size_t need = (nx + nw) * sizeof(unsigned short);

    if (ws_size >= need) {
        unsigned short* xb = (unsigned short*)d_ws;
        unsigned short* Wb = xb + nx;
        int nx8 = (int)(nx / 8), nw8 = (int)(nw / 8);
        int tot8 = nx8 + nw8;
        cvt_bf16_kernel<<<dim3((tot8 + 255) / 256), dim3(256), 0, stream>>>(x, xb, nx8, W, Wb, nw8);
        int nwg = (F / 256) * (B / 128);    // 1024, divisible by 8
        gemm_bn_256n_kernel<<<dim3(nwg), dim3(512), 0, stream>>>(xb, Wb, gamma, beta, prior, out, B, F, K);
    } else {
        dim3 g1(F / 128, B / 128);
        gemm_bn_kernel<<<g1, dim3(256), 0, stream>>>(x, W, gamma, beta, prior, out, B, F, K);
    }
    sparsemax_kernel<<<dim3(B / 4), dim3(256), 0, stream>>>(out, B, F);
}

// Round 12
// 140.315 us; speedup vs baseline: 1.1956x; 1.0430x over previous
//
#include <hip/hip_runtime.h>
#include <hip/hip_bf16.h>

#define BN_EPS 1e-5f

typedef __attribute__((ext_vector_type(8))) short bf16x8;
typedef __attribute__((ext_vector_type(4))) float f32x4;

__device__ __forceinline__ unsigned short f2bf(float f) {
    union { float f; unsigned u; } x; x.f = f;
    unsigned u = x.u;
    unsigned r = (u + 0x7fffu + ((u >> 16) & 1u)) >> 16;  // RTNE
    return (unsigned short)r;
}

// ---------------- f32 -> bf16 pre-conversion for x and W in one launch ----------------
__global__ __launch_bounds__(256) void cvt_bf16_kernel(
    const float* __restrict__ x, unsigned short* __restrict__ xb, int nx8,
    const float* __restrict__ W, unsigned short* __restrict__ Wb, int nw8)
{
    int i = blockIdx.x * 256 + threadIdx.x;
    const float* in; unsigned short* out; int idx;
    if (i < nx8) { in = x; out = xb; idx = i; }
    else if (i < nx8 + nw8) { in = W; out = Wb; idx = i - nx8; }
    else return;
    const float4* p = reinterpret_cast<const float4*>(in) + (size_t)idx * 2;
    float4 lo = p[0], hi = p[1];
    union { unsigned short us[8]; uint4 v; } pk;
    pk.us[0] = f2bf(lo.x); pk.us[1] = f2bf(lo.y); pk.us[2] = f2bf(lo.z); pk.us[3] = f2bf(lo.w);
    pk.us[4] = f2bf(hi.x); pk.us[5] = f2bf(hi.y); pk.us[6] = f2bf(hi.z); pk.us[7] = f2bf(hi.w);
    reinterpret_cast<uint4*>(out)[idx] = pk.v;
}

// ---------------- 128x128 GEMM + ghostBN + prior-scale, counted-vmcnt pipeline ----------------
// r9's geometry (proven 0-conflict swizzle, 4 waves, proven epilogue) + T4 done right:
// double-buffered LDS; per K-step {frags+MFMA on buf[cur] -> barrier(all reads done) ->
// STAGE(buf[cur], t+2) -> vmcnt(8) (t+1's 8 oldest landed; t+2's 8 stay IN FLIGHT across
// the barrier) -> barrier}. No vmcnt(0) drain in steady state: each tile's loads get a
// full MFMA phase + 2 barriers to land. All waits explicit asm + sched_barrier fences.
__global__ __launch_bounds__(256, 2) void gemm_bn_pipe_kernel(
    const unsigned short* __restrict__ xb,  // [B, K] bf16
    const unsigned short* __restrict__ Wb,  // [F, K] bf16
    const float* __restrict__ gamma,
    const float* __restrict__ beta,
    const float* __restrict__ prior,
    float* __restrict__ z,
    int B, int F, int K)
{
    const int tid  = threadIdx.x;
    const int lane = tid & 63;
    const int wid  = tid >> 6;
    const int wr   = wid >> 1;
    const int wc   = wid & 1;
    const int l15  = lane & 15;
    const int lq   = lane >> 4;

    // XCD-chunked bijective swizzle (nwg = 2048, divisible by 8), bx-inner (r9-proven).
    const int nwg = gridDim.x;
    const int cpx = nwg >> 3;
    const int id  = blockIdx.x;
    const int sw  = (id & 7) * cpx + (id >> 3);
    const int nbx = F >> 7;                 // 16
    const int bx  = sw & (nbx - 1);
    const int by  = sw / nbx;
    const int row0 = by * 128;
    const int col0 = bx * 128;

    __shared__ __align__(16) unsigned short As[2][128 * 64];  // 2 x 16 KB
    __shared__ __align__(16) unsigned short Bs[2][128 * 64];  // 2 x 16 KB
    __shared__ float red[2][128][2];

    f32x4 acc[4][4];
    const f32x4 zero = {0.f, 0.f, 0.f, 0.f};
#pragma unroll
    for (int m = 0; m < 4; ++m)
#pragma unroll
        for (int n = 0; n < 4; ++n) acc[m][n] = zero;

    const int cbase = wid * 256 + lane;

    // 8 gload_lds per wave per call (4 A + 4 B), linear LDS dest, pre-swizzled src.
    auto STAGE = [&](int buf, int k0) {
#pragma unroll
        for (int j = 0; j < 4; ++j) {
            int c = cbase + j * 64;
            int row = c >> 3;
            int s_src = (c & 7) ^ (row & 7);
            unsigned ldsoff = (unsigned)(wid * 4 + j) * 1024;  // bytes, wave-uniform
            {
                const unsigned short* g = xb + (size_t)(row0 + row) * K + k0 + s_src * 8;
                __builtin_amdgcn_global_load_lds(
                    (const __attribute__((address_space(1))) void*)g,
                    (__attribute__((address_space(3))) void*)((char*)As[buf] + ldsoff),
                    16, 0, 0);
            }
            {
                const unsigned short* g = Wb + (size_t)(col0 + row) * K + k0 + s_src * 8;
                __builtin_amdgcn_global_load_lds(
                    (const __attribute__((address_space(1))) void*)g,
                    (__attribute__((address_space(3))) void*)((char*)Bs[buf] + ldsoff),
                    16, 0, 0);
            }
        }
    };

    const int NT = K >> 6;  // 8

    // Prologue: stage tiles 0 and 1; wait only for tile 0's 8 (oldest), tile 1 in flight.
    STAGE(0, 0);
    STAGE(1, 64);
    asm volatile("s_waitcnt vmcnt(8)" ::: "memory");
    __builtin_amdgcn_sched_barrier(0);
    __builtin_amdgcn_s_barrier();
    __builtin_amdgcn_sched_barrier(0);

    int cur = 0;
    for (int t = 0; t < NT; ++t) {
        // ---- compute on buf[cur] (fully landed for all waves by loop invariant) ----
#pragma unroll
        for (int ks = 0; ks < 2; ++ks) {
            bf16x8 af[4], bfr[4];
#pragma unroll
            for (int m = 0; m < 4; ++m) {
                int r = wr * 64 + m * 16 + l15;
                int s = ks * 4 + lq;
                af[m] = *reinterpret_cast<const bf16x8*>(&As[cur][r * 64 + ((s ^ (r & 7)) * 8)]);
            }
#pragma unroll
            for (int n = 0; n < 4; ++n) {
                int r = wc * 64 + n * 16 + l15;
                int s = ks * 4 + lq;
                bfr[n] = *reinterpret_cast<const bf16x8*>(&Bs[cur][r * 64 + ((s ^ (r & 7)) * 8)]);
            }
            asm volatile("s_waitcnt lgkmcnt(0)" ::: "memory");
            __builtin_amdgcn_sched_barrier(0);
            __builtin_amdgcn_s_setprio(1);
#pragma unroll
            for (int m = 0; m < 4; ++m)
#pragma unroll
                for (int n = 0; n < 4; ++n)
                    acc[m][n] = __builtin_amdgcn_mfma_f32_16x16x32_bf16(af[m], bfr[n], acc[m][n], 0, 0, 0);
            __builtin_amdgcn_s_setprio(0);
        }

        // ---- all waves done reading buf[cur] ----
        __builtin_amdgcn_sched_barrier(0);
        __builtin_amdgcn_s_barrier();
        __builtin_amdgcn_sched_barrier(0);

        // ---- refill buf[cur] with tile t+2; counted wait: tile t+1's 8 oldest landed ----
        if (t + 2 < NT) {
            STAGE(cur, (t + 2) << 6);
            asm volatile("s_waitcnt vmcnt(8)" ::: "memory");
        } else {
            asm volatile("s_waitcnt vmcnt(0)" ::: "memory");
        }
        __builtin_amdgcn_sched_barrier(0);
        __builtin_amdgcn_s_barrier();   // after this, buf[cur^1] (tile t+1) complete for ALL waves
        __builtin_amdgcn_sched_barrier(0);
        cur ^= 1;
    }

    // ---- GhostBN stats: per-column sum/sumsq over this block's 128 rows ----
    float psum[4], psq[4];
#pragma unroll
    for (int n = 0; n < 4; ++n) {
        float s = 0.f, q = 0.f;
#pragma unroll
        for (int m = 0; m < 4; ++m)
#pragma unroll
            for (int r = 0; r < 4; ++r) { float v = acc[m][n][r]; s += v; q += v * v; }
        s += __shfl_xor(s, 16); q += __shfl_xor(q, 16);
        s += __shfl_xor(s, 32); q += __shfl_xor(q, 32);
        psum[n] = s; psq[n] = q;
    }
    if (lane < 16) {
#pragma unroll
        for (int n = 0; n < 4; ++n) {
            red[wr][wc * 64 + n * 16 + lane][0] = psum[n];
            red[wr][wc * 64 + n * 16 + lane][1] = psq[n];
        }
    }
    __syncthreads();

    // ---- epilogue: BN + prior scale, read prior at store site (r9-proven) ----
#pragma unroll
    for (int n = 0; n < 4; ++n) {
        int cl = wc * 64 + n * 16 + l15;
        int cg = col0 + cl;
        float tot = red[0][cl][0] + red[1][cl][0];
        float tsq = red[0][cl][1] + red[1][cl][1];
        float mu  = tot * (1.f / 128.f);
        float var = tsq * (1.f / 128.f) - mu * mu;
        float rv  = rsqrtf(var + BN_EPS);
        float g   = gamma[cg] * rv;
        float bt  = beta[cg] - mu * g;
#pragma unroll
        for (int m = 0; m < 4; ++m) {
#pragma unroll
            for (int r = 0; r < 4; ++r) {
                int rg = row0 + wr * 64 + m * 16 + lq * 4 + r;
                size_t idx = (size_t)rg * F + cg;
                z[idx] = (acc[m][n][r] * g + bt) * prior[idx];
            }
        }
    }
}

// ---------------- fallback (f32 inputs, in-loop convert) ----------------
__global__ __launch_bounds__(256, 2) void gemm_bn_kernel(
    const float* __restrict__ x, const float* __restrict__ W,
    const float* __restrict__ gamma, const float* __restrict__ beta,
    const float* __restrict__ prior, float* __restrict__ z,
    int B, int F, int K)
{
    const int tid  = threadIdx.x;
    const int lane = tid & 63;
    const int wid  = tid >> 6;
    const int wr   = wid >> 1;
    const int wc   = wid & 1;
    const int row0 = blockIdx.y * 128;
    const int col0 = blockIdx.x * 128;
    const int l15  = lane & 15;
    const int lq   = lane >> 4;

    __shared__ __align__(16) unsigned short As[128 * 64];
    __shared__ __align__(16) unsigned short Bs[128 * 64];
    __shared__ float red[2][128][2];

    f32x4 acc[4][4];
    const f32x4 zero = {0.f, 0.f, 0.f, 0.f};
#pragma unroll
    for (int m = 0; m < 4; ++m)
#pragma unroll
        for (int n = 0; n < 4; ++n) acc[m][n] = zero;

    for (int k0 = 0; k0 < K; k0 += 64) {
#pragma unroll
        for (int i = 0; i < 4; ++i) {
            int c = tid + i * 256;
            int r = c >> 3;
            int s = c & 7;
            {
                const float4* pa = reinterpret_cast<const float4*>(x + (size_t)(row0 + r) * K + k0 + s * 8);
                float4 lo = pa[0], hi = pa[1];
                union { unsigned short us[8]; uint4 v; } pk;
                pk.us[0] = f2bf(lo.x); pk.us[1] = f2bf(lo.y); pk.us[2] = f2bf(lo.z); pk.us[3] = f2bf(lo.w);
                pk.us[4] = f2bf(hi.x); pk.us[5] = f2bf(hi.y); pk.us[6] = f2bf(hi.z); pk.us[7] = f2bf(hi.w);
                *reinterpret_cast<uint4*>(&As[r * 64 + ((s ^ (r & 7)) * 8)]) = pk.v;
            }
            {
                const float4* pb = reinterpret_cast<const float4*>(W + (size_t)(col0 + r) * K + k0 + s * 8);
                float4 lo = pb[0], hi = pb[1];
                union { unsigned short us[8]; uint4 v; } pk;
                pk.us[0] = f2bf(lo.x); pk.us[1] = f2bf(lo.y); pk.us[2] = f2bf(lo.z); pk.us[3] = f2bf(lo.w);
                pk.us[4] = f2bf(hi.x); pk.us[5] = f2bf(hi.y); pk.us[6] = f2bf(hi.z); pk.us[7] = f2bf(hi.w);
                *reinterpret_cast<uint4*>(&Bs[r * 64 + ((s ^ (r & 7)) * 8)]) = pk.v;
            }
        }
        __syncthreads();
#pragma unroll
        for (int ks = 0; ks < 2; ++ks) {
            bf16x8 af[4], bfr[4];
#pragma unroll
            for (int m = 0; m < 4; ++m) {
                int r = wr * 64 + m * 16 + l15;
                int s = ks * 4 + lq;
                af[m] = *reinterpret_cast<const bf16x8*>(&As[r * 64 + ((s ^ (r & 7)) * 8)]);
            }
#pragma unroll
            for (int n = 0; n < 4; ++n) {
                int r = wc * 64 + n * 16 + l15;
                int s = ks * 4 + lq;
                bfr[n] = *reinterpret_cast<const bf16x8*>(&Bs[r * 64 + ((s ^ (r & 7)) * 8)]);
            }
#pragma unroll
            for (int m = 0; m < 4; ++m)
#pragma unroll
                for (int n = 0; n < 4; ++n)
                    acc[m][n] = __builtin_amdgcn_mfma_f32_16x16x32_bf16(af[m], bfr[n], acc[m][n], 0, 0, 0);
        }
        __syncthreads();
    }

    float psum[4], psq[4];
#pragma unroll
    for (int n = 0; n < 4; ++n) {
        float s = 0.f, q = 0.f;
#pragma unroll
        for (int m = 0; m < 4; ++m)
#pragma unroll
            for (int r = 0; r < 4; ++r) { float v = acc[m][n][r]; s += v; q += v * v; }
        s += __shfl_xor(s, 16); q += __shfl_xor(q, 16);
        s += __shfl_xor(s, 32); q += __shfl_xor(q, 32);
        psum[n] = s; psq[n] = q;
    }
    if (lane < 16) {
#pragma unroll
        for (int n = 0; n < 4; ++n) {
            red[wr][wc * 64 + n * 16 + lane][0] = psum[n];
            red[wr][wc * 64 + n * 16 + lane][1] = psq[n];
        }
    }
    __syncthreads();

#pragma unroll
    for (int n = 0; n < 4; ++n) {
        int cl = wc * 64 + n * 16 + l15;
        int cg = col0 + cl;
        float tot = red[0][cl][0] + red[1][cl][0];
        float tsq = red[0][cl][1] + red[1][cl][1];
        float mu  = tot * (1.f / 128.f);
        float var = tsq * (1.f / 128.f) - mu * mu;
        float rv  = rsqrtf(var + BN_EPS);
        float g   = gamma[cg] * rv;
        float bt  = beta[cg] - mu * g;
#pragma unroll
        for (int m = 0; m < 4; ++m) {
#pragma unroll
            for (int r = 0; r < 4; ++r) {
                int rg = row0 + wr * 64 + m * 16 + lq * 4 + r;
                size_t idx = (size_t)rg * F + cg;
                z[idx] = (acc[m][n][r] * g + bt) * prior[idx];
            }
        }
    }
}

// ---------------- sparsemax (Michelot fixed-point), one wave per row ----------------
__global__ __launch_bounds__(256, 4) void sparsemax_kernel(float* __restrict__ z, int B, int F)
{
    const int lane = threadIdx.x & 63;
    const int wid  = threadIdx.x >> 6;
    const int row  = blockIdx.x * 4 + wid;
    if (row >= B) return;
    float* rp = z + (size_t)row * F;

    float4 v[8];
    float s = 0.f;
#pragma unroll
    for (int j = 0; j < 8; ++j) {
        v[j] = reinterpret_cast<const float4*>(rp)[j * 64 + lane];
        s += v[j].x + v[j].y + v[j].z + v[j].w;
    }
#pragma unroll
    for (int o = 32; o; o >>= 1) s += __shfl_xor(s, o);

    float tau = (s - 1.f) / (float)F;
    int cprev = F;
    for (int it = 0; it < 64; ++it) {
        float s2 = 0.f; int c2 = 0;
#pragma unroll
        for (int j = 0; j < 8; ++j) {
            if (v[j].x > tau) { s2 += v[j].x; ++c2; }
            if (v[j].y > tau) { s2 += v[j].y; ++c2; }
            if (v[j].z > tau) { s2 += v[j].z; ++c2; }
            if (v[j].w > tau) { s2 += v[j].w; ++c2; }
        }
#pragma unroll
        for (int o = 32; o; o >>= 1) { s2 += __shfl_xor(s2, o); c2 += __shfl_xor(c2, o); }
        if (c2 == cprev) break;
        tau = (s2 - 1.f) / (float)c2;
        cprev = c2;
    }

#pragma unroll
    for (int j = 0; j < 8; ++j) {
        float4 o4;
        o4.x = fmaxf(v[j].x - tau, 0.f);
        o4.y = fmaxf(v[j].y - tau, 0.f);
        o4.z = fmaxf(v[j].z - tau, 0.f);
        o4.w = fmaxf(v[j].w - tau, 0.f);
        reinterpret_cast<float4*>(rp)[j * 64 + lane] = o4;
    }
}

extern "C" void kernel_launch(void* const* d_in, const int* in_sizes, int n_in,
                              void* d_out, int out_size, void* d_ws, size_t ws_size,
                              hipStream_t stream) {
    const float* x     = (const float*)d_in[0];
    const float* prior = (const float*)d_in[1];
    const float* W     = (const float*)d_in[2];
    const float* gamma = (const float*)d_in[3];
    const float* beta  = (const float*)d_in[4];
    float* out = (float*)d_out;

    const int F = in_sizes[3];              // 2048
    const int K = in_sizes[2] / F;          // 512
    const int B = in_sizes[0] / K;          // 16384

    const size_t nx = (size_t)B * K;
    const size_t nw = (size_t)F * K;
    const size_t need = (nx + nw) * sizeof(unsigned short);

    if (ws_size >= need) {
        unsigned short* xb = (unsigned short*)d_ws;
        unsigned short* Wb = xb + nx;
        int nx8 = (int)(nx / 8), nw8 = (int)(nw / 8);
        int tot8 = nx8 + nw8;
        cvt_bf16_kernel<<<dim3((tot8 + 255) / 256), dim3(256), 0, stream>>>(x, xb, nx8, W, Wb, nw8);
        int nwg = (F / 128) * (B / 128);    // 2048, divisible by 8
        gemm_bn_pipe_kernel<<<dim3(nwg), dim3(256), 0, stream>>>(xb, Wb, gamma, beta, prior, out, B, F, K);
    } else {
        dim3 g1(F / 128, B / 128);
        gemm_bn_kernel<<<g1, dim3(256), 0, stream>>>(x, W, gamma, beta, prior, out, B, F, K);
    }
    sparsemax_kernel<<<dim3(B / 4), dim3(256), 0, stream>>>(out, B, F);
}

// Round 13
// 135.991 us; speedup vs baseline: 1.2336x; 1.0318x over previous
//
#include <hip/hip_runtime.h>
#include <hip/hip_bf16.h>

#define BN_EPS 1e-5f

typedef __attribute__((ext_vector_type(8))) short bf16x8;
typedef __attribute__((ext_vector_type(4))) float f32x4;

__device__ __forceinline__ unsigned short f2bf(float f) {
    union { float f; unsigned u; } x; x.f = f;
    unsigned u = x.u;
    unsigned r = (u + 0x7fffu + ((u >> 16) & 1u)) >> 16;  // RTNE
    return (unsigned short)r;
}

// ---------------- f32 -> bf16 pre-conversion for x and W in one launch ----------------
__global__ __launch_bounds__(256) void cvt_bf16_kernel(
    const float* __restrict__ x, unsigned short* __restrict__ xb, int nx8,
    const float* __restrict__ W, unsigned short* __restrict__ Wb, int nw8)
{
    int i = blockIdx.x * 256 + threadIdx.x;
    const float* in; unsigned short* out; int idx;
    if (i < nx8) { in = x; out = xb; idx = i; }
    else if (i < nx8 + nw8) { in = W; out = Wb; idx = i - nx8; }
    else return;
    const float4* p = reinterpret_cast<const float4*>(in) + (size_t)idx * 2;
    float4 lo = p[0], hi = p[1];
    union { unsigned short us[8]; uint4 v; } pk;
    pk.us[0] = f2bf(lo.x); pk.us[1] = f2bf(lo.y); pk.us[2] = f2bf(lo.z); pk.us[3] = f2bf(lo.w);
    pk.us[4] = f2bf(hi.x); pk.us[5] = f2bf(hi.y); pk.us[6] = f2bf(hi.z); pk.us[7] = f2bf(hi.w);
    reinterpret_cast<uint4*>(out)[idx] = pk.v;
}

// ---------------- 128x128 GEMM + ghostBN + prior-scale, COALESCED epilogue ----------------
// K-loop/staging/swizzle/stats = r9-proven (single-buffer, straight-line STAGE->bar->
// compute->bar, global_load_lds w=16, 0-conflict XOR swizzle, XCD bx-inner swizzle).
// NEW: the epilogue re-layouts the acc tile through LDS (64x132 f32, reusing the As/Bs
// space) so prior reads and z writes are float4 with 512B contiguous segments per wave
// instruction (vs 64B scalar before) — attacks the measured ~2.8 TB/s effective-BW cap.
__global__ __launch_bounds__(256, 4) void gemm_bn_cw_kernel(
    const unsigned short* __restrict__ xb,  // [B, K] bf16
    const unsigned short* __restrict__ Wb,  // [F, K] bf16
    const float* __restrict__ gamma,
    const float* __restrict__ beta,
    const float* __restrict__ prior,
    float* __restrict__ z,
    int B, int F, int K)
{
    const int tid  = threadIdx.x;
    const int lane = tid & 63;
    const int wid  = tid >> 6;
    const int wr   = wid >> 1;
    const int wc   = wid & 1;
    const int l15  = lane & 15;
    const int lq   = lane >> 4;

    // XCD-chunked bijective swizzle (nwg = 2048, divisible by 8), bx-inner.
    const int nwg = gridDim.x;
    const int cpx = nwg >> 3;
    const int id  = blockIdx.x;
    const int sw  = (id & 7) * cpx + (id >> 3);
    const int nbx = F >> 7;                 // 16
    const int bx  = sw & (nbx - 1);
    const int by  = sw / nbx;
    const int row0 = by * 128;
    const int col0 = bx * 128;

    // 33 KB shared region: As(16K)+Bs(16K) during K-loop; 64x132 f32 tile in epilogue.
    __shared__ __align__(16) unsigned char SMRAW[33792];
    unsigned short* As = (unsigned short*)SMRAW;
    unsigned short* Bs = (unsigned short*)(SMRAW + 16384);
    float* EP = (float*)SMRAW;              // [64][132] padded f32
    __shared__ float red[2][128][2];
    __shared__ __align__(16) float gls[128];
    __shared__ __align__(16) float bls[128];

    f32x4 acc[4][4];
    const f32x4 zero = {0.f, 0.f, 0.f, 0.f};
#pragma unroll
    for (int m = 0; m < 4; ++m)
#pragma unroll
        for (int n = 0; n < 4; ++n) acc[m][n] = zero;

    const int cbase = wid * 256 + lane;

    for (int k0 = 0; k0 < K; k0 += 64) {
        // ---- STAGE tile (straight-line, same basic block as the protecting barrier) ----
#pragma unroll
        for (int j = 0; j < 4; ++j) {
            int c = cbase + j * 64;
            int row = c >> 3;
            int s_src = (c & 7) ^ (row & 7);
            unsigned ldsoff = (unsigned)(wid * 4 + j) * 1024;  // bytes, wave-uniform
            {
                const unsigned short* g = xb + (size_t)(row0 + row) * K + k0 + s_src * 8;
                __builtin_amdgcn_global_load_lds(
                    (const __attribute__((address_space(1))) void*)g,
                    (__attribute__((address_space(3))) void*)((char*)As + ldsoff),
                    16, 0, 0);
            }
            {
                const unsigned short* g = Wb + (size_t)(col0 + row) * K + k0 + s_src * 8;
                __builtin_amdgcn_global_load_lds(
                    (const __attribute__((address_space(1))) void*)g,
                    (__attribute__((address_space(3))) void*)((char*)Bs + ldsoff),
                    16, 0, 0);
            }
        }
        __syncthreads();

#pragma unroll
        for (int ks = 0; ks < 2; ++ks) {
            bf16x8 af[4], bfr[4];
#pragma unroll
            for (int m = 0; m < 4; ++m) {
                int r = wr * 64 + m * 16 + l15;
                int s = ks * 4 + lq;
                af[m] = *reinterpret_cast<const bf16x8*>(&As[r * 64 + ((s ^ (r & 7)) * 8)]);
            }
#pragma unroll
            for (int n = 0; n < 4; ++n) {
                int r = wc * 64 + n * 16 + l15;
                int s = ks * 4 + lq;
                bfr[n] = *reinterpret_cast<const bf16x8*>(&Bs[r * 64 + ((s ^ (r & 7)) * 8)]);
            }
#pragma unroll
            for (int m = 0; m < 4; ++m)
#pragma unroll
                for (int n = 0; n < 4; ++n)
                    acc[m][n] = __builtin_amdgcn_mfma_f32_16x16x32_bf16(af[m], bfr[n], acc[m][n], 0, 0, 0);
        }
        __syncthreads();
    }

    // ---- GhostBN stats: per-column sum/sumsq over this block's 128 rows ----
    float psum[4], psq[4];
#pragma unroll
    for (int n = 0; n < 4; ++n) {
        float s = 0.f, q = 0.f;
#pragma unroll
        for (int m = 0; m < 4; ++m)
#pragma unroll
            for (int r = 0; r < 4; ++r) { float v = acc[m][n][r]; s += v; q += v * v; }
        s += __shfl_xor(s, 16); q += __shfl_xor(q, 16);
        s += __shfl_xor(s, 32); q += __shfl_xor(q, 32);
        psum[n] = s; psq[n] = q;
    }
    if (lane < 16) {
#pragma unroll
        for (int n = 0; n < 4; ++n) {
            red[wr][wc * 64 + n * 16 + lane][0] = psum[n];
            red[wr][wc * 64 + n * 16 + lane][1] = psq[n];
        }
    }
    __syncthreads();

    // ---- per-column affine coefficients into LDS (once) ----
    if (tid < 128) {
        float tot = red[0][tid][0] + red[1][tid][0];
        float tsq = red[0][tid][1] + red[1][tid][1];
        float mu  = tot * (1.f / 128.f);
        float var = tsq * (1.f / 128.f) - mu * mu;
        float rv  = rsqrtf(var + BN_EPS);
        float g   = gamma[col0 + tid] * rv;
        gls[tid] = g;
        bls[tid] = beta[col0 + tid] - mu * g;
    }
    __syncthreads();

    // ---- coalesced epilogue: two passes of 64 rows via LDS re-layout ----
#pragma unroll
    for (int p = 0; p < 2; ++p) {
        if (wr == p) {
#pragma unroll
            for (int m = 0; m < 4; ++m)
#pragma unroll
                for (int n = 0; n < 4; ++n) {
                    int cc = wc * 64 + n * 16 + l15;
#pragma unroll
                    for (int r = 0; r < 4; ++r) {
                        int rr = m * 16 + lq * 4 + r;
                        EP[rr * 132 + cc] = acc[m][n][r];
                    }
                }
        }
        __syncthreads();

        // stream out: 2048 float4 units, 8 per thread; lanes 0..31 cover one full
        // 512B row-segment of prior/z -> fully coalesced loads and stores.
#pragma unroll
        for (int j = 0; j < 8; ++j) {
            int idx = j * 256 + tid;
            int rr  = idx >> 5;        // 0..63
            int c4  = idx & 31;        // 0..31 (float4 within 128 cols)
            size_t gidx = (size_t)(row0 + p * 64 + rr) * F + col0 + c4 * 4;
            float4 a  = *reinterpret_cast<const float4*>(&EP[rr * 132 + c4 * 4]);
            float4 pv = *reinterpret_cast<const float4*>(&prior[gidx]);
            float4 gg = *reinterpret_cast<const float4*>(&gls[c4 * 4]);
            float4 bb = *reinterpret_cast<const float4*>(&bls[c4 * 4]);
            float4 o;
            o.x = fmaf(a.x, gg.x, bb.x) * pv.x;
            o.y = fmaf(a.y, gg.y, bb.y) * pv.y;
            o.z = fmaf(a.z, gg.z, bb.z) * pv.z;
            o.w = fmaf(a.w, gg.w, bb.w) * pv.w;
            *reinterpret_cast<float4*>(&z[gidx]) = o;
        }
        __syncthreads();   // EP reads done before next pass overwrites
    }
}

// ---------------- fallback (f32 inputs, in-loop convert) ----------------
__global__ __launch_bounds__(256, 2) void gemm_bn_kernel(
    const float* __restrict__ x, const float* __restrict__ W,
    const float* __restrict__ gamma, const float* __restrict__ beta,
    const float* __restrict__ prior, float* __restrict__ z,
    int B, int F, int K)
{
    const int tid  = threadIdx.x;
    const int lane = tid & 63;
    const int wid  = tid >> 6;
    const int wr   = wid >> 1;
    const int wc   = wid & 1;
    const int row0 = blockIdx.y * 128;
    const int col0 = blockIdx.x * 128;
    const int l15  = lane & 15;
    const int lq   = lane >> 4;

    __shared__ __align__(16) unsigned short As[128 * 64];
    __shared__ __align__(16) unsigned short Bs[128 * 64];
    __shared__ float red[2][128][2];

    f32x4 acc[4][4];
    const f32x4 zero = {0.f, 0.f, 0.f, 0.f};
#pragma unroll
    for (int m = 0; m < 4; ++m)
#pragma unroll
        for (int n = 0; n < 4; ++n) acc[m][n] = zero;

    for (int k0 = 0; k0 < K; k0 += 64) {
#pragma unroll
        for (int i = 0; i < 4; ++i) {
            int c = tid + i * 256;
            int r = c >> 3;
            int s = c & 7;
            {
                const float4* pa = reinterpret_cast<const float4*>(x + (size_t)(row0 + r) * K + k0 + s * 8);
                float4 lo = pa[0], hi = pa[1];
                union { unsigned short us[8]; uint4 v; } pk;
                pk.us[0] = f2bf(lo.x); pk.us[1] = f2bf(lo.y); pk.us[2] = f2bf(lo.z); pk.us[3] = f2bf(lo.w);
                pk.us[4] = f2bf(hi.x); pk.us[5] = f2bf(hi.y); pk.us[6] = f2bf(hi.z); pk.us[7] = f2bf(hi.w);
                *reinterpret_cast<uint4*>(&As[r * 64 + ((s ^ (r & 7)) * 8)]) = pk.v;
            }
            {
                const float4* pb = reinterpret_cast<const float4*>(W + (size_t)(col0 + r) * K + k0 + s * 8);
                float4 lo = pb[0], hi = pb[1];
                union { unsigned short us[8]; uint4 v; } pk;
                pk.us[0] = f2bf(lo.x); pk.us[1] = f2bf(lo.y); pk.us[2] = f2bf(lo.z); pk.us[3] = f2bf(lo.w);
                pk.us[4] = f2bf(hi.x); pk.us[5] = f2bf(hi.y); pk.us[6] = f2bf(hi.z); pk.us[7] = f2bf(hi.w);
                *reinterpret_cast<uint4*>(&Bs[r * 64 + ((s ^ (r & 7)) * 8)]) = pk.v;
            }
        }
        __syncthreads();
#pragma unroll
        for (int ks = 0; ks < 2; ++ks) {
            bf16x8 af[4], bfr[4];
#pragma unroll
            for (int m = 0; m < 4; ++m) {
                int r = wr * 64 + m * 16 + l15;
                int s = ks * 4 + lq;
                af[m] = *reinterpret_cast<const bf16x8*>(&As[r * 64 + ((s ^ (r & 7)) * 8)]);
            }
#pragma unroll
            for (int n = 0; n < 4; ++n) {
                int r = wc * 64 + n * 16 + l15;
                int s = ks * 4 + lq;
                bfr[n] = *reinterpret_cast<const bf16x8*>(&Bs[r * 64 + ((s ^ (r & 7)) * 8)]);
            }
#pragma unroll
            for (int m = 0; m < 4; ++m)
#pragma unroll
                for (int n = 0; n < 4; ++n)
                    acc[m][n] = __builtin_amdgcn_mfma_f32_16x16x32_bf16(af[m], bfr[n], acc[m][n], 0, 0, 0);
        }
        __syncthreads();
    }

    float psum[4], psq[4];
#pragma unroll
    for (int n = 0; n < 4; ++n) {
        float s = 0.f, q = 0.f;
#pragma unroll
        for (int m = 0; m < 4; ++m)
#pragma unroll
            for (int r = 0; r < 4; ++r) { float v = acc[m][n][r]; s += v; q += v * v; }
        s += __shfl_xor(s, 16); q += __shfl_xor(q, 16);
        s += __shfl_xor(s, 32); q += __shfl_xor(q, 32);
        psum[n] = s; psq[n] = q;
    }
    if (lane < 16) {
#pragma unroll
        for (int n = 0; n < 4; ++n) {
            red[wr][wc * 64 + n * 16 + lane][0] = psum[n];
            red[wr][wc * 64 + n * 16 + lane][1] = psq[n];
        }
    }
    __syncthreads();

#pragma unroll
    for (int n = 0; n < 4; ++n) {
        int cl = wc * 64 + n * 16 + l15;
        int cg = col0 + cl;
        float tot = red[0][cl][0] + red[1][cl][0];
        float tsq = red[0][cl][1] + red[1][cl][1];
        float mu  = tot * (1.f / 128.f);
        float var = tsq * (1.f / 128.f) - mu * mu;
        float rv  = rsqrtf(var + BN_EPS);
        float g   = gamma[cg] * rv;
        float bt  = beta[cg] - mu * g;
#pragma unroll
        for (int m = 0; m < 4; ++m) {
#pragma unroll
            for (int r = 0; r < 4; ++r) {
                int rg = row0 + wr * 64 + m * 16 + lq * 4 + r;
                size_t idx = (size_t)rg * F + cg;
                z[idx] = (acc[m][n][r] * g + bt) * prior[idx];
            }
        }
    }
}

// ---------------- sparsemax (Michelot fixed-point), one wave per row ----------------
__global__ __launch_bounds__(256, 4) void sparsemax_kernel(float* __restrict__ z, int B, int F)
{
    const int lane = threadIdx.x & 63;
    const int wid  = threadIdx.x >> 6;
    const int row  = blockIdx.x * 4 + wid;
    if (row >= B) return;
    float* rp = z + (size_t)row * F;

    float4 v[8];
    float s = 0.f;
#pragma unroll
    for (int j = 0; j < 8; ++j) {
        v[j] = reinterpret_cast<const float4*>(rp)[j * 64 + lane];
        s += v[j].x + v[j].y + v[j].z + v[j].w;
    }
#pragma unroll
    for (int o = 32; o; o >>= 1) s += __shfl_xor(s, o);

    float tau = (s - 1.f) / (float)F;
    int cprev = F;
    for (int it = 0; it < 64; ++it) {
        float s2 = 0.f; int c2 = 0;
#pragma unroll
        for (int j = 0; j < 8; ++j) {
            if (v[j].x > tau) { s2 += v[j].x; ++c2; }
            if (v[j].y > tau) { s2 += v[j].y; ++c2; }
            if (v[j].z > tau) { s2 += v[j].z; ++c2; }
            if (v[j].w > tau) { s2 += v[j].w; ++c2; }
        }
#pragma unroll
        for (int o = 32; o; o >>= 1) { s2 += __shfl_xor(s2, o); c2 += __shfl_xor(c2, o); }
        if (c2 == cprev) break;
        tau = (s2 - 1.f) / (float)c2;
        cprev = c2;
    }

#pragma unroll
    for (int j = 0; j < 8; ++j) {
        float4 o4;
        o4.x = fmaxf(v[j].x - tau, 0.f);
        o4.y = fmaxf(v[j].y - tau, 0.f);
        o4.z = fmaxf(v[j].z - tau, 0.f);
        o4.w = fmaxf(v[j].w - tau, 0.f);
        reinterpret_cast<float4*>(rp)[j * 64 + lane] = o4;
    }
}

extern "C" void kernel_launch(void* const* d_in, const int* in_sizes, int n_in,
                              void* d_out, int out_size, void* d_ws, size_t ws_size,
                              hipStream_t stream) {
    const float* x     = (const float*)d_in[0];
    const float* prior = (const float*)d_in[1];
    const float* W     = (const float*)d_in[2];
    const float* gamma = (const float*)d_in[3];
    const float* beta  = (const float*)d_in[4];
    float* out = (float*)d_out;

    const int F = in_sizes[3];              // 2048
    const int K = in_sizes[2] / F;          // 512
    const int B = in_sizes[0] / K;          // 16384

    const size_t nx = (size_t)B * K;
    const size_t nw = (size_t)F * K;
    const size_t need = (nx + nw) * sizeof(unsigned short);

    if (ws_size >= need) {
        unsigned short* xb = (unsigned short*)d_ws;
        unsigned short* Wb = xb + nx;
        int nx8 = (int)(nx / 8), nw8 = (int)(nw / 8);
        int tot8 = nx8 + nw8;
        cvt_bf16_kernel<<<dim3((tot8 + 255) / 256), dim3(256), 0, stream>>>(x, xb, nx8, W, Wb, nw8);
        int nwg = (F / 128) * (B / 128);    // 2048, divisible by 8
        gemm_bn_cw_kernel<<<dim3(nwg), dim3(256), 0, stream>>>(xb, Wb, gamma, beta, prior, out, B, F, K);
    } else {
        dim3 g1(F / 128, B / 128);
        gemm_bn_kernel<<<g1, dim3(256), 0, stream>>>(x, W, gamma, beta, prior, out, B, F, K);
    }
    sparsemax_kernel<<<dim3(B / 4), dim3(256), 0, stream>>>(out, B, F);
}